// Round 2
// baseline (1009.369 us; speedup 1.0000x reference)
//
#include <hip/hip_runtime.h>

#define D     128
#define NT    200000
#define NL    50000
#define ETA   1000000
#define EREV  1000000
#define ELL   500000
#define ELBL  500000

typedef __attribute__((ext_vector_type(8))) __bf16 bf16x8;
typedef __attribute__((ext_vector_type(4))) float f32x4;
typedef __attribute__((ext_vector_type(4))) _Float16 f16x4;

__device__ inline bf16x8 cvt8(float4 a, float4 b)
{
    bf16x8 r;
    r[0] = (__bf16)a.x; r[1] = (__bf16)a.y; r[2] = (__bf16)a.z; r[3] = (__bf16)a.w;
    r[4] = (__bf16)b.x; r[5] = (__bf16)b.y; r[6] = (__bf16)b.z; r[7] = (__bf16)b.w;
    return r;
}

// ---------------------------------------------------------------------------
// Weight prep: 4 bf16 weight slots in [n][k] layout + bias_sum.
// Slot 0 = W_l_tl, 1 = W_r_tl, 2 = W_l_ll, 3 = W_r_tl + W_r_ll.
// ---------------------------------------------------------------------------
__global__ __launch_bounds__(256) void prep_weights(
    const float* __restrict__ Wl_tl, const float* __restrict__ Wr_tl,
    const float* __restrict__ Wl_ll, const float* __restrict__ Wr_ll,
    const float* __restrict__ b_tl, const float* __restrict__ b_ll,
    __bf16* __restrict__ Wb, float* __restrict__ bias_sum)
{
    int i = blockIdx.x * 256 + threadIdx.x;
    if (i < D * D) {
        Wb[i]             = (__bf16)Wl_tl[i];
        Wb[D * D + i]     = (__bf16)Wr_tl[i];
        Wb[2 * D * D + i] = (__bf16)Wl_ll[i];
        Wb[3 * D * D + i] = (__bf16)(Wr_tl[i] + Wr_ll[i]);
    }
    if (i < D) bias_sum[i] = b_tl[i] + b_ll[i];
}

// ---------------------------------------------------------------------------
// Degree count.
// ---------------------------------------------------------------------------
__global__ __launch_bounds__(256) void count_kernel(
    const int* __restrict__ dst, int* __restrict__ cnt, int E)
{
    int e = blockIdx.x * 256 + threadIdx.x;
    if (e >= E) return;
    atomicAdd(&cnt[dst[e]], 1);
}

// ---------------------------------------------------------------------------
// Order-free segment allocation: wave prefix-sum + one atomicAdd per wave.
// ---------------------------------------------------------------------------
__global__ __launch_bounds__(256) void alloc_kernel(
    const int* __restrict__ cnt, int* __restrict__ cur,
    int* __restrict__ gcnt, int n)
{
    int i = blockIdx.x * 256 + threadIdx.x;
    int lane = threadIdx.x & 63;
    int deg = (i < n) ? cnt[i] : 0;
    int incl = deg;
#pragma unroll
    for (int off = 1; off < 64; off <<= 1) {
        int v = __shfl_up(incl, off, 64);
        if (lane >= off) incl += v;
    }
    int excl = incl - deg;
    int total = __shfl(incl, 63, 64);
    int base = 0;
    if (lane == 63) base = atomicAdd(gcnt, total);
    base = __shfl(base, 63, 64);
    if (i < n) cur[i] = base + excl;
}

// ---------------------------------------------------------------------------
// CSR fill. After this, cur[row] == segment end.
// ---------------------------------------------------------------------------
__global__ __launch_bounds__(256) void fill_kernel(
    const int* __restrict__ src, const int* __restrict__ dst,
    int* __restrict__ cur, int* __restrict__ csr, int E)
{
    int e = blockIdx.x * 256 + threadIdx.x;
    if (e >= E) return;
    int pos = atomicAdd(&cur[dst[e]], 1);
    csr[pos] = src[e];
}

// ---------------------------------------------------------------------------
// Z = x_label @ {W_l_tl, W_l_ll}^T stored as fp16 [NL][128].
// SWAPPED operand order: mfma(W_frag, x_frag) -> D rows = n, D cols = x row.
// Lane (q,m15) holds x-row rBase+m15, cols n = nt*16 + q*4 + {0..3}:
// 4 consecutive elements -> 8 B vector stores, and gather-friendly layout.
// ---------------------------------------------------------------------------
__global__ __launch_bounds__(256) void z_label_gemm(
    const float* __restrict__ labelEmbed, const int* __restrict__ labelNodeId,
    const __bf16* __restrict__ Wb,
    _Float16* __restrict__ Zrev, _Float16* __restrict__ Zll)
{
    const int w = threadIdx.x >> 6;
    const int lane = threadIdx.x & 63;
    const int m15 = lane & 15, q = lane >> 4;
    const int rowOrig = blockIdx.x * 64 + w * 16 + m15;
    const int row = (rowOrig < NL) ? rowOrig : NL - 1;
    const int xr = labelNodeId[row];

    bf16x8 aE[4];
    const float* pe = labelEmbed + (size_t)xr * D + q * 8;
#pragma unroll
    for (int kc = 0; kc < 4; ++kc) {
        float4 f0 = *reinterpret_cast<const float4*>(pe + kc * 32);
        float4 f1 = *reinterpret_cast<const float4*>(pe + kc * 32 + 4);
        aE[kc] = cvt8(f0, f1);
    }

    const f32x4 z4 = {0.f, 0.f, 0.f, 0.f};
#pragma unroll
    for (int pass = 0; pass < 2; ++pass) {
        const __bf16* W = Wb + (pass ? 2 * D * D : 0);
        _Float16* Z = pass ? Zll : Zrev;
        f32x4 acc[8];
#pragma unroll
        for (int nt = 0; nt < 8; ++nt) acc[nt] = z4;
#pragma unroll
        for (int kc = 0; kc < 4; ++kc) {
#pragma unroll
            for (int nt = 0; nt < 8; ++nt) {
                bf16x8 wf = *reinterpret_cast<const bf16x8*>(
                    W + (nt * 16 + m15) * D + kc * 32 + q * 8);
                acc[nt] = __builtin_amdgcn_mfma_f32_16x16x32_bf16(wf, aE[kc], acc[nt], 0, 0, 0);
            }
        }
        if (rowOrig < NL) {
#pragma unroll
            for (int nt = 0; nt < 8; ++nt) {
                f16x4 o;
                o[0] = (_Float16)acc[nt][0]; o[1] = (_Float16)acc[nt][1];
                o[2] = (_Float16)acc[nt][2]; o[3] = (_Float16)acc[nt][3];
                *reinterpret_cast<f16x4*>(Z + (size_t)row * D + nt * 16 + q * 4) = o;
            }
        }
    }
}

// ---------------------------------------------------------------------------
// Title side (swapped layout):
//   Zta      = x_title @ W_l_tl^T            (fp16, consumed by label GEMM)
//   outTitle = relu(x_title @ W_r_tl^T + b_tl + mean(Zrev[rev_src]))
// Lane owns one x-row; epilogue rev-gather is 8 B f16x4 loads, all 16 rows
// of the wave gathered in parallel (per-lane degree loop).
// ---------------------------------------------------------------------------
__global__ __launch_bounds__(256) void gemm_title_mfma(
    const float* __restrict__ xTitle, const __bf16* __restrict__ Wb,
    const float* __restrict__ b_tl, const _Float16* __restrict__ Zrev,
    const int* __restrict__ csrRev, const int* __restrict__ cntRev,
    const int* __restrict__ curRev,
    _Float16* __restrict__ Zta, float* __restrict__ outTitle)
{
    const int w = threadIdx.x >> 6;
    const int lane = threadIdx.x & 63;
    const int m15 = lane & 15, q = lane >> 4;
    const int row = blockIdx.x * 64 + w * 16 + m15;   // NT % 64 == 0

    bf16x8 aX[4];
    const float* px = xTitle + (size_t)row * D + q * 8;
#pragma unroll
    for (int kc = 0; kc < 4; ++kc) {
        float4 g0 = *reinterpret_cast<const float4*>(px + kc * 32);
        float4 g1 = *reinterpret_cast<const float4*>(px + kc * 32 + 4);
        aX[kc] = cvt8(g0, g1);
    }

    const f32x4 z4 = {0.f, 0.f, 0.f, 0.f};
    f32x4 acc[8];

    // Pass 1: W_l_tl -> Zta (fp16).
    const __bf16* W0 = Wb;
#pragma unroll
    for (int nt = 0; nt < 8; ++nt) acc[nt] = z4;
#pragma unroll
    for (int kc = 0; kc < 4; ++kc) {
#pragma unroll
        for (int nt = 0; nt < 8; ++nt) {
            bf16x8 wf = *reinterpret_cast<const bf16x8*>(
                W0 + (nt * 16 + m15) * D + kc * 32 + q * 8);
            acc[nt] = __builtin_amdgcn_mfma_f32_16x16x32_bf16(wf, aX[kc], acc[nt], 0, 0, 0);
        }
    }
#pragma unroll
    for (int nt = 0; nt < 8; ++nt) {
        f16x4 o;
        o[0] = (_Float16)acc[nt][0]; o[1] = (_Float16)acc[nt][1];
        o[2] = (_Float16)acc[nt][2]; o[3] = (_Float16)acc[nt][3];
        *reinterpret_cast<f16x4*>(Zta + (size_t)row * D + nt * 16 + q * 4) = o;
    }

    // Pass 2: W_r_tl.
    const __bf16* W1 = Wb + D * D;
#pragma unroll
    for (int nt = 0; nt < 8; ++nt) acc[nt] = z4;
#pragma unroll
    for (int kc = 0; kc < 4; ++kc) {
#pragma unroll
        for (int nt = 0; nt < 8; ++nt) {
            bf16x8 wf = *reinterpret_cast<const bf16x8*>(
                W1 + (nt * 16 + m15) * D + kc * 32 + q * 8);
            acc[nt] = __builtin_amdgcn_mfma_f32_16x16x32_bf16(wf, aX[kc], acc[nt], 0, 0, 0);
        }
    }

    // Fused rev mean: acc += (1/deg) * sum Zrev[j].
    {
        int deg = cntRev[row];
        int end = curRev[row];
        int e = end - deg;
        float rs = 1.0f / fmaxf((float)deg, 1.0f);
        for (; e < end; ++e) {
            int j = csrRev[e];
            const _Float16* z = Zrev + (size_t)j * D + q * 4;
#pragma unroll
            for (int nt = 0; nt < 8; ++nt) {
                f16x4 zv = *reinterpret_cast<const f16x4*>(z + nt * 16);
                acc[nt][0] = fmaf((float)zv[0], rs, acc[nt][0]);
                acc[nt][1] = fmaf((float)zv[1], rs, acc[nt][1]);
                acc[nt][2] = fmaf((float)zv[2], rs, acc[nt][2]);
                acc[nt][3] = fmaf((float)zv[3], rs, acc[nt][3]);
            }
        }
    }

#pragma unroll
    for (int nt = 0; nt < 8; ++nt) {
        float4 bb = *reinterpret_cast<const float4*>(b_tl + nt * 16 + q * 4);
        float4 o;
        o.x = fmaxf(acc[nt][0] + bb.x, 0.0f);
        o.y = fmaxf(acc[nt][1] + bb.y, 0.0f);
        o.z = fmaxf(acc[nt][2] + bb.z, 0.0f);
        o.w = fmaxf(acc[nt][3] + bb.w, 0.0f);
        *reinterpret_cast<float4*>(outTitle + (size_t)row * D + nt * 16 + q * 4) = o;
    }
}

// ---------------------------------------------------------------------------
// Label side (swapped layout):
//   outLabel = relu(mean(Zta[ta_src]) + mean(Zll[ll_src])
//                   + x_label @ (Wr_tl+Wr_ll)^T + b_sum)
// Both aggregations fused as f16x4 gathers; no meanTa intermediate at all.
// ---------------------------------------------------------------------------
__global__ __launch_bounds__(256) void gemm_label_mfma(
    const float* __restrict__ labelEmbed, const int* __restrict__ labelNodeId,
    const __bf16* __restrict__ Wb, const float* __restrict__ bias_sum,
    const _Float16* __restrict__ Zta, const int* __restrict__ csrTa,
    const int* __restrict__ cntTa, const int* __restrict__ curTa,
    const _Float16* __restrict__ Zll, const int* __restrict__ csrLl,
    const int* __restrict__ cntLl, const int* __restrict__ curLl,
    float* __restrict__ outLabel)
{
    const int w = threadIdx.x >> 6;
    const int lane = threadIdx.x & 63;
    const int m15 = lane & 15, q = lane >> 4;
    const int rowOrig = blockIdx.x * 64 + w * 16 + m15;
    const int row = (rowOrig < NL) ? rowOrig : NL - 1;   // clamp (partial last block)
    const int xr = labelNodeId[row];

    bf16x8 aXl[4];
    const float* pe = labelEmbed + (size_t)xr * D + q * 8;
#pragma unroll
    for (int kc = 0; kc < 4; ++kc) {
        float4 h0 = *reinterpret_cast<const float4*>(pe + kc * 32);
        float4 h1 = *reinterpret_cast<const float4*>(pe + kc * 32 + 4);
        aXl[kc] = cvt8(h0, h1);
    }

    const f32x4 z4 = {0.f, 0.f, 0.f, 0.f};
    f32x4 acc[8];
#pragma unroll
    for (int nt = 0; nt < 8; ++nt) acc[nt] = z4;

    const __bf16* W3 = Wb + 3 * D * D;   // W_r_tl + W_r_ll
#pragma unroll
    for (int kc = 0; kc < 4; ++kc) {
#pragma unroll
        for (int nt = 0; nt < 8; ++nt) {
            bf16x8 wf = *reinterpret_cast<const bf16x8*>(
                W3 + (nt * 16 + m15) * D + kc * 32 + q * 8);
            acc[nt] = __builtin_amdgcn_mfma_f32_16x16x32_bf16(wf, aXl[kc], acc[nt], 0, 0, 0);
        }
    }

    // Fused ta mean from Zta.
    {
        int deg = cntTa[row];
        int end = curTa[row];
        int e = end - deg;
        float rs = 1.0f / fmaxf((float)deg, 1.0f);
        for (; e < end; ++e) {
            int j = csrTa[e];
            const _Float16* z = Zta + (size_t)j * D + q * 4;
#pragma unroll
            for (int nt = 0; nt < 8; ++nt) {
                f16x4 zv = *reinterpret_cast<const f16x4*>(z + nt * 16);
                acc[nt][0] = fmaf((float)zv[0], rs, acc[nt][0]);
                acc[nt][1] = fmaf((float)zv[1], rs, acc[nt][1]);
                acc[nt][2] = fmaf((float)zv[2], rs, acc[nt][2]);
                acc[nt][3] = fmaf((float)zv[3], rs, acc[nt][3]);
            }
        }
    }
    // Fused ll mean from Zll.
    {
        int deg = cntLl[row];
        int end = curLl[row];
        int e = end - deg;
        float rs = 1.0f / fmaxf((float)deg, 1.0f);
        for (; e < end; ++e) {
            int j = csrLl[e];
            const _Float16* z = Zll + (size_t)j * D + q * 4;
#pragma unroll
            for (int nt = 0; nt < 8; ++nt) {
                f16x4 zv = *reinterpret_cast<const f16x4*>(z + nt * 16);
                acc[nt][0] = fmaf((float)zv[0], rs, acc[nt][0]);
                acc[nt][1] = fmaf((float)zv[1], rs, acc[nt][1]);
                acc[nt][2] = fmaf((float)zv[2], rs, acc[nt][2]);
                acc[nt][3] = fmaf((float)zv[3], rs, acc[nt][3]);
            }
        }
    }

    if (rowOrig < NL) {
#pragma unroll
        for (int nt = 0; nt < 8; ++nt) {
            float4 bb = *reinterpret_cast<const float4*>(bias_sum + nt * 16 + q * 4);
            float4 o;
            o.x = fmaxf(acc[nt][0] + bb.x, 0.0f);
            o.y = fmaxf(acc[nt][1] + bb.y, 0.0f);
            o.z = fmaxf(acc[nt][2] + bb.z, 0.0f);
            o.w = fmaxf(acc[nt][3] + bb.w, 0.0f);
            *reinterpret_cast<float4*>(outLabel + (size_t)row * D + nt * 16 + q * 4) = o;
        }
    }
}

// ---------------------------------------------------------------------------
// Supervision-edge dot products: 32 lanes per edge, float4 per lane.
// ---------------------------------------------------------------------------
__global__ __launch_bounds__(256) void pred_kernel(
    const float* __restrict__ outTitle, const float* __restrict__ outLabel,
    const int* __restrict__ elSrc, const int* __restrict__ elDst,
    float* __restrict__ pred, int E)
{
    int idx = blockIdx.x * 256 + threadIdx.x;
    int e = idx >> 5;
    if (e >= E) return;
    int l = idx & 31;
    int s = elSrc[e];
    int d = elDst[e];
    float4 a = *reinterpret_cast<const float4*>(outTitle + (size_t)s * D + l * 4);
    float4 b = *reinterpret_cast<const float4*>(outLabel + (size_t)d * D + l * 4);
    float v = a.x * b.x + a.y * b.y + a.z * b.z + a.w * b.w;
#pragma unroll
    for (int off = 16; off > 0; off >>= 1) v += __shfl_down(v, off, 32);
    if (l == 0) pred[e] = v;
}

// ---------------------------------------------------------------------------
extern "C" void kernel_launch(void* const* d_in, const int* in_sizes, int n_in,
                              void* d_out, int out_size, void* d_ws, size_t ws_size,
                              hipStream_t stream)
{
    const float* x_title       = (const float*)d_in[0];
    const float* label_embed   = (const float*)d_in[1];
    const float* W_l_tl        = (const float*)d_in[2];
    const float* b_l_tl        = (const float*)d_in[3];
    const float* W_r_tl        = (const float*)d_in[4];
    const float* W_l_ll        = (const float*)d_in[5];
    const float* b_l_ll        = (const float*)d_in[6];
    const float* W_r_ll        = (const float*)d_in[7];
    const int*   label_node_id = (const int*)d_in[8];
    const int*   ta_src        = (const int*)d_in[9];
    const int*   ta_dst        = (const int*)d_in[10];
    const int*   rev_src       = (const int*)d_in[11];
    const int*   rev_dst       = (const int*)d_in[12];
    const int*   ll_src        = (const int*)d_in[13];
    const int*   ll_dst        = (const int*)d_in[14];
    const int*   el_src        = (const int*)d_in[15];
    const int*   el_dst        = (const int*)d_in[16];

    float* out       = (float*)d_out;
    float* pred      = out;                        // [ELBL]
    float* out_title = out + ELBL;                 // [NT*D]
    float* out_label = out_title + (size_t)NT * D; // [NL*D]

    // Workspace layout (~89.5 MB).
    __bf16*   Wb      = (__bf16*)d_ws;                     // 4*D*D bf16 = 128 KiB
    float*    bias_sum= (float*)(Wb + 4 * D * D);          // 128 floats
    _Float16* Zrev    = (_Float16*)(bias_sum + D);         // NL*D fp16 = 12.8 MB
    _Float16* Zll     = Zrev + (size_t)NL * D;             // NL*D fp16 = 12.8 MB
    _Float16* Zta     = Zll + (size_t)NL * D;              // NT*D fp16 = 51.2 MB
    int*      cntTa   = (int*)(Zta + (size_t)NT * D);      // NL
    int*      cntLl   = cntTa + NL;                        // NL
    int*      cntRev  = cntLl + NL;                        // NT
    int*      gcnt    = cntRev + NT;                       // 3
    int*      curTa   = gcnt + 3;                          // NL
    int*      curLl   = curTa + NL;                        // NL
    int*      curRev  = curLl + NL;                        // NT
    int*      csrTa   = curRev + NT;                       // ETA
    int*      csrLl   = csrTa + ETA;                       // ELL
    int*      csrRev  = csrLl + ELL;                       // EREV

    // Zero degree counters + the 3 global cursors (contiguous).
    hipMemsetAsync(cntTa, 0, (size_t)(NL + NL + NT + 3) * sizeof(int), stream);

    prep_weights<<<(D * D + 255) / 256, 256, 0, stream>>>(
        W_l_tl, W_r_tl, W_l_ll, W_r_ll, b_l_tl, b_l_ll, Wb, bias_sum);

    // Z tables (label rows through W_l_tl / W_l_ll), fp16, swapped layout.
    z_label_gemm<<<(NL + 63) / 64, 256, 0, stream>>>(
        label_embed, label_node_id, Wb, Zrev, Zll);

    // Degree histograms.
    count_kernel<<<(ETA  + 255) / 256, 256, 0, stream>>>(ta_dst,  cntTa,  ETA);
    count_kernel<<<(ELL  + 255) / 256, 256, 0, stream>>>(ll_dst,  cntLl,  ELL);
    count_kernel<<<(EREV + 255) / 256, 256, 0, stream>>>(rev_dst, cntRev, EREV);

    // Segment allocation (order-free, one atomic per wave).
    alloc_kernel<<<(NL + 255) / 256, 256, 0, stream>>>(cntTa,  curTa,  gcnt + 0, NL);
    alloc_kernel<<<(NL + 255) / 256, 256, 0, stream>>>(cntLl,  curLl,  gcnt + 1, NL);
    alloc_kernel<<<(NT + 255) / 256, 256, 0, stream>>>(cntRev, curRev, gcnt + 2, NT);

    // CSR fills (all store un-remapped source row ids — Z tables are in
    // x_label / x_title row space).
    fill_kernel<<<(ETA  + 255) / 256, 256, 0, stream>>>(ta_src,  ta_dst,  curTa,  csrTa,  ETA);
    fill_kernel<<<(ELL  + 255) / 256, 256, 0, stream>>>(ll_src,  ll_dst,  curLl,  csrLl,  ELL);
    fill_kernel<<<(EREV + 255) / 256, 256, 0, stream>>>(rev_src, rev_dst, curRev, csrRev, EREV);

    // Title GEMM: writes Zta (fp16) + outTitle (fused rev aggregation).
    gemm_title_mfma<<<NT / 64, 256, 0, stream>>>(
        x_title, Wb, b_l_tl, Zrev, csrRev, cntRev, curRev, Zta, out_title);

    // Label GEMM: fused ta + ll aggregations from Zta / Zll.
    gemm_label_mfma<<<(NL + 63) / 64, 256, 0, stream>>>(
        label_embed, label_node_id, Wb, bias_sum,
        Zta, csrTa, cntTa, curTa, Zll, csrLl, cntLl, curLl, out_label);

    // Supervision-edge dot products.
    pred_kernel<<<(ELBL * 32) / 256, 256, 0, stream>>>(
        out_title, out_label, el_src, el_dst, pred, ELBL);
}

// Round 3
// 945.134 us; speedup vs baseline: 1.0680x; 1.0680x over previous
//
#include <hip/hip_runtime.h>

#define D     128
#define NT    200000
#define NL    50000
#define ETA   1000000
#define EREV  1000000
#define ELL   500000
#define ELBL  500000

typedef __attribute__((ext_vector_type(8))) __bf16 bf16x8;
typedef __attribute__((ext_vector_type(4))) float f32x4;
typedef __attribute__((ext_vector_type(4))) _Float16 f16x4;
typedef __attribute__((ext_vector_type(8))) _Float16 f16x8;

__device__ inline bf16x8 cvt8(float4 a, float4 b)
{
    bf16x8 r;
    r[0] = (__bf16)a.x; r[1] = (__bf16)a.y; r[2] = (__bf16)a.z; r[3] = (__bf16)a.w;
    r[4] = (__bf16)b.x; r[5] = (__bf16)b.y; r[6] = (__bf16)b.z; r[7] = (__bf16)b.w;
    return r;
}

// Build f16x8 from two f32x4 accumulators (for permuted Z stores).
__device__ inline f16x8 pack8(const f32x4& a, const f32x4& b)
{
    f16x8 o;
    o[0] = (_Float16)a[0]; o[1] = (_Float16)a[1];
    o[2] = (_Float16)a[2]; o[3] = (_Float16)a[3];
    o[4] = (_Float16)b[0]; o[5] = (_Float16)b[1];
    o[6] = (_Float16)b[2]; o[7] = (_Float16)b[3];
    return o;
}

// ---------------------------------------------------------------------------
// Z tables use a PERMUTED per-row layout matching the MFMA C-fragment:
//   Z_perm[row][q*32 + nt*4 + i]  ==  Z[row][nt*16 + q*4 + i]
// so the 32 cols owned by lane q are one contiguous 64 B block ->
// gathers become 4 x dwordx4 per edge per lane (1 cacheline per lane).
// ---------------------------------------------------------------------------

// ---------------------------------------------------------------------------
// Weight prep: 4 bf16 weight slots in [n][k] layout + bias_sum.
// Slot 0 = W_l_tl, 1 = W_r_tl, 2 = W_l_ll, 3 = W_r_tl + W_r_ll.
// ---------------------------------------------------------------------------
__global__ __launch_bounds__(256) void prep_weights(
    const float* __restrict__ Wl_tl, const float* __restrict__ Wr_tl,
    const float* __restrict__ Wl_ll, const float* __restrict__ Wr_ll,
    const float* __restrict__ b_tl, const float* __restrict__ b_ll,
    __bf16* __restrict__ Wb, float* __restrict__ bias_sum)
{
    int i = blockIdx.x * 256 + threadIdx.x;
    if (i < D * D) {
        Wb[i]             = (__bf16)Wl_tl[i];
        Wb[D * D + i]     = (__bf16)Wr_tl[i];
        Wb[2 * D * D + i] = (__bf16)Wl_ll[i];
        Wb[3 * D * D + i] = (__bf16)(Wr_tl[i] + Wr_ll[i]);
    }
    if (i < D) bias_sum[i] = b_tl[i] + b_ll[i];
}

// ---------------------------------------------------------------------------
// Degree count.
// ---------------------------------------------------------------------------
__global__ __launch_bounds__(256) void count_kernel(
    const int* __restrict__ dst, int* __restrict__ cnt, int E)
{
    int e = blockIdx.x * 256 + threadIdx.x;
    if (e >= E) return;
    atomicAdd(&cnt[dst[e]], 1);
}

// ---------------------------------------------------------------------------
// Order-free segment allocation: wave prefix-sum + one atomicAdd per wave.
// ---------------------------------------------------------------------------
__global__ __launch_bounds__(256) void alloc_kernel(
    const int* __restrict__ cnt, int* __restrict__ cur,
    int* __restrict__ gcnt, int n)
{
    int i = blockIdx.x * 256 + threadIdx.x;
    int lane = threadIdx.x & 63;
    int deg = (i < n) ? cnt[i] : 0;
    int incl = deg;
#pragma unroll
    for (int off = 1; off < 64; off <<= 1) {
        int v = __shfl_up(incl, off, 64);
        if (lane >= off) incl += v;
    }
    int excl = incl - deg;
    int total = __shfl(incl, 63, 64);
    int base = 0;
    if (lane == 63) base = atomicAdd(gcnt, total);
    base = __shfl(base, 63, 64);
    if (i < n) cur[i] = base + excl;
}

// ---------------------------------------------------------------------------
// CSR fill. After this, cur[row] == segment end.
// ---------------------------------------------------------------------------
__global__ __launch_bounds__(256) void fill_kernel(
    const int* __restrict__ src, const int* __restrict__ dst,
    int* __restrict__ cur, int* __restrict__ csr, int E)
{
    int e = blockIdx.x * 256 + threadIdx.x;
    if (e >= E) return;
    int pos = atomicAdd(&cur[dst[e]], 1);
    csr[pos] = src[e];
}

// ---------------------------------------------------------------------------
// Zrev/Zll = x_label @ {W_l_tl, W_l_ll}^T, fp16, PERMUTED layout.
// Swapped mfma(W, x): lane (q,m15) holds x-row base+m15, cols nt*16+q*4+{0..3}.
// ---------------------------------------------------------------------------
__global__ __launch_bounds__(256) void z_label_gemm(
    const float* __restrict__ labelEmbed, const int* __restrict__ labelNodeId,
    const __bf16* __restrict__ Wb,
    _Float16* __restrict__ Zrev, _Float16* __restrict__ Zll)
{
    const int w = threadIdx.x >> 6;
    const int lane = threadIdx.x & 63;
    const int m15 = lane & 15, q = lane >> 4;
    const int rowOrig = blockIdx.x * 64 + w * 16 + m15;
    const int row = (rowOrig < NL) ? rowOrig : NL - 1;
    const int xr = labelNodeId[row];

    bf16x8 aE[4];
    const float* pe = labelEmbed + (size_t)xr * D + q * 8;
#pragma unroll
    for (int kc = 0; kc < 4; ++kc) {
        float4 f0 = *reinterpret_cast<const float4*>(pe + kc * 32);
        float4 f1 = *reinterpret_cast<const float4*>(pe + kc * 32 + 4);
        aE[kc] = cvt8(f0, f1);
    }

    const f32x4 z4 = {0.f, 0.f, 0.f, 0.f};
#pragma unroll
    for (int pass = 0; pass < 2; ++pass) {
        const __bf16* W = Wb + (pass ? 2 * D * D : 0);
        _Float16* Z = pass ? Zll : Zrev;
        f32x4 acc[8];
#pragma unroll
        for (int nt = 0; nt < 8; ++nt) acc[nt] = z4;
#pragma unroll
        for (int kc = 0; kc < 4; ++kc) {
#pragma unroll
            for (int nt = 0; nt < 8; ++nt) {
                bf16x8 wf = *reinterpret_cast<const bf16x8*>(
                    W + (nt * 16 + m15) * D + kc * 32 + q * 8);
                acc[nt] = __builtin_amdgcn_mfma_f32_16x16x32_bf16(wf, aE[kc], acc[nt], 0, 0, 0);
            }
        }
        if (rowOrig < NL) {
            f16x8* zp = reinterpret_cast<f16x8*>(Z + (size_t)row * D + q * 32);
#pragma unroll
            for (int k = 0; k < 4; ++k)
                zp[k] = pack8(acc[2 * k], acc[2 * k + 1]);
        }
    }
}

// ---------------------------------------------------------------------------
// Title side:
//   Zta      = x_title @ W_l_tl^T   (fp16, permuted; consumed by label GEMM)
//   outTitle = relu(x_title @ W_r_tl^T + b_tl + mean(Zrev[rev_src]))
// Gather: 4 x dwordx4 contiguous per edge per lane; packed f16 accumulate
// (v_pk_add_f16, 16 VALU/edge instead of 64), merged to f32 once at end.
// ---------------------------------------------------------------------------
__global__ __launch_bounds__(256) void gemm_title_mfma(
    const float* __restrict__ xTitle, const __bf16* __restrict__ Wb,
    const float* __restrict__ b_tl, const _Float16* __restrict__ Zrev,
    const int* __restrict__ csrRev, const int* __restrict__ cntRev,
    const int* __restrict__ curRev,
    _Float16* __restrict__ Zta, float* __restrict__ outTitle)
{
    const int w = threadIdx.x >> 6;
    const int lane = threadIdx.x & 63;
    const int m15 = lane & 15, q = lane >> 4;
    const int row = blockIdx.x * 64 + w * 16 + m15;   // NT % 64 == 0

    bf16x8 aX[4];
    const float* px = xTitle + (size_t)row * D + q * 8;
#pragma unroll
    for (int kc = 0; kc < 4; ++kc) {
        float4 g0 = *reinterpret_cast<const float4*>(px + kc * 32);
        float4 g1 = *reinterpret_cast<const float4*>(px + kc * 32 + 4);
        aX[kc] = cvt8(g0, g1);
    }

    const f32x4 z4 = {0.f, 0.f, 0.f, 0.f};
    f32x4 acc[8];

    // Pass 1: W_l_tl -> Zta (fp16, permuted).
    const __bf16* W0 = Wb;
#pragma unroll
    for (int nt = 0; nt < 8; ++nt) acc[nt] = z4;
#pragma unroll
    for (int kc = 0; kc < 4; ++kc) {
#pragma unroll
        for (int nt = 0; nt < 8; ++nt) {
            bf16x8 wf = *reinterpret_cast<const bf16x8*>(
                W0 + (nt * 16 + m15) * D + kc * 32 + q * 8);
            acc[nt] = __builtin_amdgcn_mfma_f32_16x16x32_bf16(wf, aX[kc], acc[nt], 0, 0, 0);
        }
    }
    {
        f16x8* zp = reinterpret_cast<f16x8*>(Zta + (size_t)row * D + q * 32);
#pragma unroll
        for (int k = 0; k < 4; ++k)
            zp[k] = pack8(acc[2 * k], acc[2 * k + 1]);
    }

    // Pass 2: W_r_tl.
    const __bf16* W1 = Wb + D * D;
#pragma unroll
    for (int nt = 0; nt < 8; ++nt) acc[nt] = z4;
#pragma unroll
    for (int kc = 0; kc < 4; ++kc) {
#pragma unroll
        for (int nt = 0; nt < 8; ++nt) {
            bf16x8 wf = *reinterpret_cast<const bf16x8*>(
                W1 + (nt * 16 + m15) * D + kc * 32 + q * 8);
            acc[nt] = __builtin_amdgcn_mfma_f32_16x16x32_bf16(wf, aX[kc], acc[nt], 0, 0, 0);
        }
    }

    // Fused rev mean: packed-f16 accumulate over edges, then one merge.
    {
        int deg = cntRev[row];
        int end = curRev[row];
        int e = end - deg;
        f16x8 gsum[4];
#pragma unroll
        for (int k = 0; k < 4; ++k)
#pragma unroll
            for (int h = 0; h < 8; ++h) gsum[k][h] = (_Float16)0.f;
        for (; e < end; ++e) {
            int j = csrRev[e];
            const f16x8* zp = reinterpret_cast<const f16x8*>(
                Zrev + (size_t)j * D + q * 32);
#pragma unroll
            for (int k = 0; k < 4; ++k) gsum[k] += zp[k];
        }
        float rs = 1.0f / fmaxf((float)deg, 1.0f);
#pragma unroll
        for (int k = 0; k < 4; ++k)
#pragma unroll
            for (int h = 0; h < 8; ++h) {
                int idx = k * 8 + h;          // = nt*4 + i
                acc[idx >> 2][idx & 3] += rs * (float)gsum[k][h];
            }
    }

#pragma unroll
    for (int nt = 0; nt < 8; ++nt) {
        float4 bb = *reinterpret_cast<const float4*>(b_tl + nt * 16 + q * 4);
        float4 o;
        o.x = fmaxf(acc[nt][0] + bb.x, 0.0f);
        o.y = fmaxf(acc[nt][1] + bb.y, 0.0f);
        o.z = fmaxf(acc[nt][2] + bb.z, 0.0f);
        o.w = fmaxf(acc[nt][3] + bb.w, 0.0f);
        *reinterpret_cast<float4*>(outTitle + (size_t)row * D + nt * 16 + q * 4) = o;
    }
}

// ---------------------------------------------------------------------------
// Label side:
//   outLabel = relu(mean(Zta[ta_src]) + mean(Zll[ll_src])
//                   + x_label @ (Wr_tl+Wr_ll)^T + b_sum)
// Both gathers use the permuted contiguous pattern + packed f16 accumulate.
// ---------------------------------------------------------------------------
__global__ __launch_bounds__(256) void gemm_label_mfma(
    const float* __restrict__ labelEmbed, const int* __restrict__ labelNodeId,
    const __bf16* __restrict__ Wb, const float* __restrict__ bias_sum,
    const _Float16* __restrict__ Zta, const int* __restrict__ csrTa,
    const int* __restrict__ cntTa, const int* __restrict__ curTa,
    const _Float16* __restrict__ Zll, const int* __restrict__ csrLl,
    const int* __restrict__ cntLl, const int* __restrict__ curLl,
    float* __restrict__ outLabel)
{
    const int w = threadIdx.x >> 6;
    const int lane = threadIdx.x & 63;
    const int m15 = lane & 15, q = lane >> 4;
    const int rowOrig = blockIdx.x * 64 + w * 16 + m15;
    const int row = (rowOrig < NL) ? rowOrig : NL - 1;   // clamp (partial last block)
    const int xr = labelNodeId[row];

    bf16x8 aXl[4];
    const float* pe = labelEmbed + (size_t)xr * D + q * 8;
#pragma unroll
    for (int kc = 0; kc < 4; ++kc) {
        float4 h0 = *reinterpret_cast<const float4*>(pe + kc * 32);
        float4 h1 = *reinterpret_cast<const float4*>(pe + kc * 32 + 4);
        aXl[kc] = cvt8(h0, h1);
    }

    const f32x4 z4 = {0.f, 0.f, 0.f, 0.f};
    f32x4 acc[8];
#pragma unroll
    for (int nt = 0; nt < 8; ++nt) acc[nt] = z4;

    const __bf16* W3 = Wb + 3 * D * D;   // W_r_tl + W_r_ll
#pragma unroll
    for (int kc = 0; kc < 4; ++kc) {
#pragma unroll
        for (int nt = 0; nt < 8; ++nt) {
            bf16x8 wf = *reinterpret_cast<const bf16x8*>(
                W3 + (nt * 16 + m15) * D + kc * 32 + q * 8);
            acc[nt] = __builtin_amdgcn_mfma_f32_16x16x32_bf16(wf, aXl[kc], acc[nt], 0, 0, 0);
        }
    }

    // Two fused means (ta from Zta, ll from Zll), sequential so gsum regs reuse.
#pragma unroll
    for (int pass = 0; pass < 2; ++pass) {
        const _Float16* Z = pass ? Zll : Zta;
        const int* csr = pass ? csrLl : csrTa;
        int deg = pass ? cntLl[row] : cntTa[row];
        int end = pass ? curLl[row] : curTa[row];
        int e = end - deg;
        f16x8 gsum[4];
#pragma unroll
        for (int k = 0; k < 4; ++k)
#pragma unroll
            for (int h = 0; h < 8; ++h) gsum[k][h] = (_Float16)0.f;
        for (; e < end; ++e) {
            int j = csr[e];
            const f16x8* zp = reinterpret_cast<const f16x8*>(
                Z + (size_t)j * D + q * 32);
#pragma unroll
            for (int k = 0; k < 4; ++k) gsum[k] += zp[k];
        }
        float rs = 1.0f / fmaxf((float)deg, 1.0f);
#pragma unroll
        for (int k = 0; k < 4; ++k)
#pragma unroll
            for (int h = 0; h < 8; ++h) {
                int idx = k * 8 + h;          // = nt*4 + i
                acc[idx >> 2][idx & 3] += rs * (float)gsum[k][h];
            }
    }

    if (rowOrig < NL) {
#pragma unroll
        for (int nt = 0; nt < 8; ++nt) {
            float4 bb = *reinterpret_cast<const float4*>(bias_sum + nt * 16 + q * 4);
            float4 o;
            o.x = fmaxf(acc[nt][0] + bb.x, 0.0f);
            o.y = fmaxf(acc[nt][1] + bb.y, 0.0f);
            o.z = fmaxf(acc[nt][2] + bb.z, 0.0f);
            o.w = fmaxf(acc[nt][3] + bb.w, 0.0f);
            *reinterpret_cast<float4*>(outLabel + (size_t)row * D + nt * 16 + q * 4) = o;
        }
    }
}

// ---------------------------------------------------------------------------
// Supervision-edge dot products: 32 lanes per edge, float4 per lane.
// ---------------------------------------------------------------------------
__global__ __launch_bounds__(256) void pred_kernel(
    const float* __restrict__ outTitle, const float* __restrict__ outLabel,
    const int* __restrict__ elSrc, const int* __restrict__ elDst,
    float* __restrict__ pred, int E)
{
    int idx = blockIdx.x * 256 + threadIdx.x;
    int e = idx >> 5;
    if (e >= E) return;
    int l = idx & 31;
    int s = elSrc[e];
    int d = elDst[e];
    float4 a = *reinterpret_cast<const float4*>(outTitle + (size_t)s * D + l * 4);
    float4 b = *reinterpret_cast<const float4*>(outLabel + (size_t)d * D + l * 4);
    float v = a.x * b.x + a.y * b.y + a.z * b.z + a.w * b.w;
#pragma unroll
    for (int off = 16; off > 0; off >>= 1) v += __shfl_down(v, off, 32);
    if (l == 0) pred[e] = v;
}

// ---------------------------------------------------------------------------
extern "C" void kernel_launch(void* const* d_in, const int* in_sizes, int n_in,
                              void* d_out, int out_size, void* d_ws, size_t ws_size,
                              hipStream_t stream)
{
    const float* x_title       = (const float*)d_in[0];
    const float* label_embed   = (const float*)d_in[1];
    const float* W_l_tl        = (const float*)d_in[2];
    const float* b_l_tl        = (const float*)d_in[3];
    const float* W_r_tl        = (const float*)d_in[4];
    const float* W_l_ll        = (const float*)d_in[5];
    const float* b_l_ll        = (const float*)d_in[6];
    const float* W_r_ll        = (const float*)d_in[7];
    const int*   label_node_id = (const int*)d_in[8];
    const int*   ta_src        = (const int*)d_in[9];
    const int*   ta_dst        = (const int*)d_in[10];
    const int*   rev_src       = (const int*)d_in[11];
    const int*   rev_dst       = (const int*)d_in[12];
    const int*   ll_src        = (const int*)d_in[13];
    const int*   ll_dst        = (const int*)d_in[14];
    const int*   el_src        = (const int*)d_in[15];
    const int*   el_dst        = (const int*)d_in[16];

    float* out       = (float*)d_out;
    float* pred      = out;                        // [ELBL]
    float* out_title = out + ELBL;                 // [NT*D]
    float* out_label = out_title + (size_t)NT * D; // [NL*D]

    // Workspace layout (~89.5 MB).
    __bf16*   Wb      = (__bf16*)d_ws;                     // 4*D*D bf16 = 128 KiB
    float*    bias_sum= (float*)(Wb + 4 * D * D);          // 128 floats
    _Float16* Zrev    = (_Float16*)(bias_sum + D);         // NL*D fp16 = 12.8 MB
    _Float16* Zll     = Zrev + (size_t)NL * D;             // NL*D fp16 = 12.8 MB
    _Float16* Zta     = Zll + (size_t)NL * D;              // NT*D fp16 = 51.2 MB
    int*      cntTa   = (int*)(Zta + (size_t)NT * D);      // NL
    int*      cntLl   = cntTa + NL;                        // NL
    int*      cntRev  = cntLl + NL;                        // NT
    int*      gcnt    = cntRev + NT;                       // 3
    int*      curTa   = gcnt + 3;                          // NL
    int*      curLl   = curTa + NL;                        // NL
    int*      curRev  = curLl + NL;                        // NT
    int*      csrTa   = curRev + NT;                       // ETA
    int*      csrLl   = csrTa + ETA;                       // ELL
    int*      csrRev  = csrLl + ELL;                       // EREV

    // Zero degree counters + the 3 global cursors (contiguous).
    hipMemsetAsync(cntTa, 0, (size_t)(NL + NL + NT + 3) * sizeof(int), stream);

    prep_weights<<<(D * D + 255) / 256, 256, 0, stream>>>(
        W_l_tl, W_r_tl, W_l_ll, W_r_ll, b_l_tl, b_l_ll, Wb, bias_sum);

    // Z tables (label rows through W_l_tl / W_l_ll), fp16 permuted layout.
    z_label_gemm<<<(NL + 63) / 64, 256, 0, stream>>>(
        label_embed, label_node_id, Wb, Zrev, Zll);

    // Degree histograms.
    count_kernel<<<(ETA  + 255) / 256, 256, 0, stream>>>(ta_dst,  cntTa,  ETA);
    count_kernel<<<(ELL  + 255) / 256, 256, 0, stream>>>(ll_dst,  cntLl,  ELL);
    count_kernel<<<(EREV + 255) / 256, 256, 0, stream>>>(rev_dst, cntRev, EREV);

    // Segment allocation (order-free, one atomic per wave).
    alloc_kernel<<<(NL + 255) / 256, 256, 0, stream>>>(cntTa,  curTa,  gcnt + 0, NL);
    alloc_kernel<<<(NL + 255) / 256, 256, 0, stream>>>(cntLl,  curLl,  gcnt + 1, NL);
    alloc_kernel<<<(NT + 255) / 256, 256, 0, stream>>>(cntRev, curRev, gcnt + 2, NT);

    // CSR fills (store un-remapped source row ids).
    fill_kernel<<<(ETA  + 255) / 256, 256, 0, stream>>>(ta_src,  ta_dst,  curTa,  csrTa,  ETA);
    fill_kernel<<<(ELL  + 255) / 256, 256, 0, stream>>>(ll_src,  ll_dst,  curLl,  csrLl,  ELL);
    fill_kernel<<<(EREV + 255) / 256, 256, 0, stream>>>(rev_src, rev_dst, curRev, csrRev, EREV);

    // Title GEMM: writes Zta (fp16 permuted) + outTitle (fused rev mean).
    gemm_title_mfma<<<NT / 64, 256, 0, stream>>>(
        x_title, Wb, b_l_tl, Zrev, csrRev, cntRev, curRev, Zta, out_title);

    // Label GEMM: fused ta + ll means from Zta / Zll.
    gemm_label_mfma<<<(NL + 63) / 64, 256, 0, stream>>>(
        label_embed, label_node_id, Wb, bias_sum,
        Zta, csrTa, cntTa, curTa, Zll, csrLl, cntLl, curLl, out_label);

    // Supervision-edge dot products.
    pred_kernel<<<(ELBL * 32) / 256, 256, 0, stream>>>(
        out_title, out_label, el_src, el_dst, pred, ELBL);
}